// Round 11
// baseline (82.013 us; speedup 1.0000x reference)
//
#include <hip/hip_runtime.h>
#include <hip/hip_bf16.h>

#define NBLK 8
#define DIN 512
#define DOUT 512
#define NFEAT 4096      // NBLK * DIN
#define BATCH 8192
#define NT 16           // DIN / 32 K-steps
#define BM 128
#define BN 256

typedef __attribute__((ext_vector_type(8))) short short8;
typedef __attribute__((ext_vector_type(4))) float f32x4;

static __device__ __forceinline__ short f2bf16(float f) {
  __bf16 h = (__bf16)f;               // RNE; compiler packs into v_cvt_pk_bf16_f32
  return __builtin_bit_cast(short, h);
}

static __device__ __forceinline__ short8 cvt8(f32x4 lo, f32x4 hi) {
  short8 o;
  o[0] = f2bf16(lo[0]); o[1] = f2bf16(lo[1]); o[2] = f2bf16(lo[2]); o[3] = f2bf16(lo[3]);
  o[4] = f2bf16(hi[0]); o[5] = f2bf16(hi[1]); o[6] = f2bf16(hi[2]); o[7] = f2bf16(hi[3]);
  return o;
}

static __device__ __forceinline__ void gload_lds16(const void* g, void* l) {
  __builtin_amdgcn_global_load_lds(
      (const __attribute__((address_space(1))) void*)g,
      (__attribute__((address_space(3))) void*)l, 16, 0, 0);
}

// Pre-pass: W [8][512][512] fp32 -> Wp fragment-major bf16. Chunk (nb,cb,t)
// is 1 KB contiguous: lane l holds col cb*16+(l&15), k = t*32+(l>>4)*8.
__global__ __launch_bounds__(256) void wprep_kernel(const float* __restrict__ W,
                                                    short* __restrict__ Wp) {
  const int gid  = blockIdx.x * 256 + threadIdx.x;
  const int lane = gid & 63;
  const int t    = (gid >> 6) & 15;
  const int cb   = (gid >> 10) & 31;
  const int nb   = gid >> 15;
  const int col  = cb * 16 + (lane & 15);
  const int k    = t * 32 + (lane >> 4) * 8;
  const float* src = W + (size_t)(nb * DOUT + col) * DIN + k;
  f32x4 lo = *(const f32x4*)src;
  f32x4 hi = *(const f32x4*)(src + 4);
  *(short8*)(Wp + (size_t)gid * 8) = cvt8(lo, hi);
}

// R11: occupancy round. 128x256 block, 512 threads, 8 waves = 2 M-rows x
// 4 N-cols, wave tile 64x64 (4x4 frags = 64 acc VGPR -> <=128 total).
// LDS = 2-buf A (2x16KB) + 2-buf B (2x16KB) = 64 KB -> 2 BLOCKS/CU.
// Distance-1 staging with vmcnt(0)+barrier per step: the drain stall is
// covered by the co-resident block (what 144KB/1-block could never do).
// 2-deep dbuf race-free: each ds_read's data is consumed by a pre-barrier
// MFMA (compiler lgkmcnt), so post-barrier DMA overwrites can't corrupt.
template <bool WPREP>
__global__ __launch_bounds__(512, 4) void blocklinear_kernel(
    const float* __restrict__ x, const float* __restrict__ W,
    const short* __restrict__ Wp, const float* __restrict__ bias,
    float* __restrict__ y)
{
  // XCD swizzle (bijective: 1024 % 8 == 0): one nb per XCD, nt innermost
  // (2 nt-siblings share an x M-panel on one XCD's L2/L3 path).
  const int b       = blockIdx.x;
  const int logical = (b & 7) * 128 + (b >> 3);
  const int nb  = logical >> 7;
  const int rem = logical & 127;
  const int mt  = rem >> 1;    // 0..63
  const int nt  = rem & 1;     // 0..1

  const int tid  = threadIdx.x;
  const int lane = tid & 63;
  const int w    = tid >> 6;   // wave 0..7
  const int wr   = w >> 2;     // M-row 0..1 (rows wr*64..+64)
  const int wn   = w & 3;      // N-col 0..3 (cols wn*64..+64)
  const int l15  = lane & 15;
  const int k16  = lane >> 4;

  __shared__ __align__(16) float Abuf[2][BM * 32];   // 2 x 16 KB
  __shared__ __align__(16) short Bbuf[2][BN * 32];   // 2 x 16 KB  (64 KB total)

  // --- A staging: 16 x 1KB DMAs cover 128 rows x 128 B; wave w does 2
  // (rows w*16+i*8 .. +8). lane l -> row +(l>>3), dest chunk l&7 (linear);
  // source pre-swizzled chunk (l&7)^(l>>3): stored slot s = data chunk s^(row&7).
  const int l8 = lane >> 3;
  const int c  = lane & 7;
  const float* asrc[2];
#pragma unroll
  for (int i = 0; i < 2; ++i) {
    const int gr = mt * BM + w * 16 + i * 8 + l8;
    asrc[i] = x + (size_t)gr * NFEAT + nb * DIN + ((c ^ l8) << 2);
  }
  // --- B staging: 16 x 1KB chunks (one per 16-col frag); wave w does 2.
  const short* bsrc[2];
#pragma unroll
  for (int i = 0; i < 2; ++i) {
    const int cb = nt * 16 + w * 2 + i;
    bsrc[i] = WPREP ? Wp + ((size_t)(nb * 32 + cb) * 16) * 512 + lane * 8 : nullptr;
  }

#define STAGE(buf, t)                                                       \
  {                                                                         \
    _Pragma("unroll")                                                       \
    for (int i = 0; i < 2; ++i)                                             \
      gload_lds16(asrc[i] + (t) * 32, &Abuf[buf][(w * 16 + i * 8) * 32]);   \
    if constexpr (WPREP) {                                                  \
      _Pragma("unroll")                                                     \
      for (int i = 0; i < 2; ++i)                                           \
        gload_lds16(bsrc[i] + (t) * 512, &Bbuf[buf][(w * 2 + i) * 512]);    \
    }                                                                       \
  }

  // --- A fragment read offsets (floats): row = wr*64 + m*16 + l15
  // (row&7 == l15&7); addr = row*32 + slot*4, slot = (2k16 / 2k16+1)^(l15&7).
  const int ra_base = (wr * 64 + l15) * 32;
  const int ra_lo   = ra_base + (((2 * k16)     ^ (l15 & 7)) << 2);
  const int ra_hi   = ra_base + (((2 * k16 + 1) ^ (l15 & 7)) << 2);

  f32x4 acc[4][4];
#pragma unroll
  for (int m = 0; m < 4; ++m)
#pragma unroll
    for (int n = 0; n < 4; ++n)
      acc[m][n] = (f32x4){0.f, 0.f, 0.f, 0.f};

#define COMPUTE(buf)                                                        \
  {                                                                         \
    const float* la = &Abuf[buf][0];                                        \
    const short* lb = &Bbuf[buf][0];                                        \
    short8 af[4], bf[4];                                                    \
    _Pragma("unroll")                                                       \
    for (int m = 0; m < 4; ++m) {                                           \
      f32x4 lo = *(const f32x4*)(la + m * 512 + ra_lo);                     \
      f32x4 hi = *(const f32x4*)(la + m * 512 + ra_hi);                     \
      af[m] = cvt8(lo, hi);                                                 \
    }                                                                       \
    if constexpr (WPREP) {                                                  \
      _Pragma("unroll")                                                     \
      for (int n = 0; n < 4; ++n)                                           \
        bf[n] = *(const short8*)(lb + (wn * 4 + n) * 512 + lane * 8);       \
    } else {                                                                \
      _Pragma("unroll")                                                     \
      for (int n = 0; n < 4; ++n) {                                         \
        const int col = nt * BN + wn * 64 + n * 16 + l15;                   \
        const float* bp = W + (size_t)nb * DOUT * DIN + (size_t)col * DIN + \
                          CUR_T * 32 + k16 * 8;                             \
        bf[n] = cvt8(*(const f32x4*)bp, *(const f32x4*)(bp + 4));           \
      }                                                                     \
    }                                                                       \
    __builtin_amdgcn_s_setprio(1);                                          \
    _Pragma("unroll")                                                       \
    for (int m = 0; m < 4; ++m)                                             \
      _Pragma("unroll")                                                     \
      for (int n = 0; n < 4; ++n)                                           \
        acc[m][n] = __builtin_amdgcn_mfma_f32_16x16x32_bf16(af[m], bf[n], acc[m][n], 0, 0, 0); \
    __builtin_amdgcn_s_setprio(0);                                          \
  }

  // Step t: drain stage(t) (issued last step; covered by last step's compute
  // AND by the co-resident block); barrier; stage(t+1) into the buffer whose
  // reads were all consumed before the barrier; compute(t).
#define STEP(t)                                                             \
  {                                                                         \
    const int CUR_T = (t);                                                  \
    (void)CUR_T;                                                            \
    __builtin_amdgcn_sched_barrier(0);                                      \
    asm volatile("s_waitcnt vmcnt(0)" ::: "memory");                        \
    __builtin_amdgcn_s_barrier();                                           \
    __builtin_amdgcn_sched_barrier(0);                                      \
    if ((t) + 1 < NT) STAGE(((t) + 1) & 1, (t) + 1);                        \
    COMPUTE((t) & 1);                                                       \
  }

  STAGE(0, 0);

  STEP(0)  STEP(1)  STEP(2)  STEP(3)
  STEP(4)  STEP(5)  STEP(6)  STEP(7)
  STEP(8)  STEP(9)  STEP(10) STEP(11)
  STEP(12) STEP(13) STEP(14) STEP(15)

  // epilogue: C/D layout col = lane&15, row = (lane>>4)*4 + j  [m89-verified]
  const int col0 = nt * BN + wn * 64;
  const int row0 = mt * BM + wr * 64;
  const float* bptr = bias + nb * DOUT + col0;
#pragma unroll
  for (int n = 0; n < 4; ++n) {
    const float bv = bptr[n * 16 + l15];
    const size_t col = (size_t)nb * DOUT + col0 + n * 16 + l15;
#pragma unroll
    for (int m = 0; m < 4; ++m) {
      const int row = row0 + m * 16 + k16 * 4;
      float* yp = y + (size_t)row * NFEAT + col;
#pragma unroll
      for (int j = 0; j < 4; ++j)
        yp[(size_t)j * NFEAT] = acc[m][n][j] + bv;
    }
  }
}

extern "C" void kernel_launch(void* const* d_in, const int* in_sizes, int n_in,
                              void* d_out, int out_size, void* d_ws, size_t ws_size,
                              hipStream_t stream) {
  const float* x  = (const float*)d_in[0];
  const float* W  = (const float*)d_in[1];
  const float* bi = (const float*)d_in[2];
  float* y = (float*)d_out;
  const size_t wp_bytes = (size_t)NBLK * DOUT * DIN * sizeof(short);  // 4 MiB
  const int grid = NBLK * (BATCH / BM) * (DOUT / BN);                 // 1024

  if (ws_size >= wp_bytes) {
    short* Wp = (short*)d_ws;
    wprep_kernel<<<(NBLK * DOUT * DIN / 8) / 256, 256, 0, stream>>>(W, Wp);
    blocklinear_kernel<true><<<grid, 512, 0, stream>>>(x, W, Wp, bi, y);
  } else {
    blocklinear_kernel<false><<<grid, 512, 0, stream>>>(x, W, nullptr, bi, y);
  }
}